// Round 1
// baseline (2030.722 us; speedup 1.0000x reference)
//
#include <hip/hip_runtime.h>
#include <math.h>

#define B_ 4
#define T_ 2048
#define DM_ 1024
#define H_ 16
#define D_ 64
#define BT_ 16
#define NC_ 128

__device__ __forceinline__ float wredsum(float v) {
  v += __shfl_xor(v, 32);
  v += __shfl_xor(v, 16);
  v += __shfl_xor(v, 8);
  v += __shfl_xor(v, 4);
  v += __shfl_xor(v, 2);
  v += __shfl_xor(v, 1);
  return v;
}

// ---------------- RoPE tables: cos/sin (T x 32) ----------------
__global__ void k_rope_table(float* __restrict__ cosT, float* __restrict__ sinT) {
  int idx = blockIdx.x * blockDim.x + threadIdx.x;
  if (idx >= T_ * 32) return;
  int t = idx >> 5, i = idx & 31;
  float inv = powf(10000.0f, -((float)(2 * i)) / 64.0f);
  float f = (float)t * inv;
  cosT[idx] = cosf(f);
  sinT[idx] = sinf(f);
}

// ---------------- eta = 0.01*sigmoid(x @ Wlr^T), (B*T,) ----------------
__global__ __launch_bounds__(256) void k_eta(const float* __restrict__ x,
                                             const float* __restrict__ Wlr,
                                             float* __restrict__ eta) {
  int w = threadIdx.x >> 6, l = threadIdx.x & 63;
  int row = blockIdx.x * 4 + w;  // row < 8192
  const float* xr = x + (size_t)row * DM_;
  float s = 0.f;
#pragma unroll
  for (int j = 0; j < DM_ / 64; ++j) s += xr[j * 64 + l] * Wlr[j * 64 + l];
  s = wredsum(s);
  if (l == 0) eta[row] = 0.01f / (1.0f + expf(-s));
}

// ---------------- fused QKV GEMM: y = x @ W^T, scatter to (B,H,T,D) ----------------
// grid: (8192/128, 3072/128) ; block 256
__global__ __launch_bounds__(256) void k_gemm_qkv(const float* __restrict__ x,
                                                  const float* __restrict__ Wq,
                                                  const float* __restrict__ Wk,
                                                  const float* __restrict__ Wv,
                                                  float* __restrict__ qo,
                                                  float* __restrict__ ko,
                                                  float* __restrict__ vo) {
  __shared__ float As[16][128];
  __shared__ float Bs[16][128];
  int tid = threadIdx.x;
  int tx = tid & 15, ty = tid >> 4;
  int m0 = blockIdx.x * 128;
  int ng = blockIdx.y * 128;
  int mat = ng >> 10;         // 0:q 1:k 2:v  (128 | 1024, so a tile never straddles)
  int n0 = ng & 1023;
  const float* Wp = (mat == 0) ? Wq : ((mat == 1) ? Wk : Wv);
  float* op = (mat == 0) ? qo : ((mat == 1) ? ko : vo);
  float c[8][8];
#pragma unroll
  for (int i = 0; i < 8; ++i)
#pragma unroll
    for (int j = 0; j < 8; ++j) c[i][j] = 0.f;

  for (int k0 = 0; k0 < DM_; k0 += 16) {
#pragma unroll
    for (int j = 0; j < 2; ++j) {
      int f = tid * 2 + j;       // 0..511
      int row = f >> 2;          // 0..127
      int kq = f & 3;            // 0..3
      float4 av = *(const float4*)&x[(m0 + row) * DM_ + k0 + kq * 4];
      As[kq * 4 + 0][row] = av.x; As[kq * 4 + 1][row] = av.y;
      As[kq * 4 + 2][row] = av.z; As[kq * 4 + 3][row] = av.w;
      float4 bv = *(const float4*)&Wp[(n0 + row) * DM_ + k0 + kq * 4];
      Bs[kq * 4 + 0][row] = bv.x; Bs[kq * 4 + 1][row] = bv.y;
      Bs[kq * 4 + 2][row] = bv.z; Bs[kq * 4 + 3][row] = bv.w;
    }
    __syncthreads();
#pragma unroll
    for (int kk = 0; kk < 16; ++kk) {
      float a[8], b[8];
      *(float4*)&a[0] = *(float4*)&As[kk][ty * 4];
      *(float4*)&a[4] = *(float4*)&As[kk][64 + ty * 4];
      *(float4*)&b[0] = *(float4*)&Bs[kk][tx * 4];
      *(float4*)&b[4] = *(float4*)&Bs[kk][64 + tx * 4];
#pragma unroll
      for (int i = 0; i < 8; ++i)
#pragma unroll
        for (int j = 0; j < 8; ++j) c[i][j] += a[i] * b[j];
    }
    __syncthreads();
  }
  // epilogue: scatter to (B,H,T,D)
#pragma unroll
  for (int i = 0; i < 8; ++i) {
    int m = m0 + ((i < 4) ? (ty * 4 + i) : (64 + ty * 4 + i - 4));
    int bb = m >> 11, t = m & (T_ - 1);
#pragma unroll
    for (int jh = 0; jh < 2; ++jh) {
      int n = n0 + jh * 64 + tx * 4;
      int h = n >> 6, d = n & 63;
      float4 vv = make_float4(c[i][jh * 4 + 0], c[i][jh * 4 + 1],
                              c[i][jh * 4 + 2], c[i][jh * 4 + 3]);
      *(float4*)&op[((bb * H_ + h) * T_ + t) * D_ + d] = vv;
    }
  }
}

// ---------------- output GEMM: out = z @ Wo^T ----------------
// grid: (8192/128, 1024/128) ; block 256
__global__ __launch_bounds__(256) void k_gemm_out(const float* __restrict__ z,
                                                  const float* __restrict__ Wo,
                                                  float* __restrict__ out) {
  __shared__ float As[16][128];
  __shared__ float Bs[16][128];
  int tid = threadIdx.x;
  int tx = tid & 15, ty = tid >> 4;
  int m0 = blockIdx.x * 128;
  int n0 = blockIdx.y * 128;
  float c[8][8];
#pragma unroll
  for (int i = 0; i < 8; ++i)
#pragma unroll
    for (int j = 0; j < 8; ++j) c[i][j] = 0.f;

  for (int k0 = 0; k0 < DM_; k0 += 16) {
#pragma unroll
    for (int j = 0; j < 2; ++j) {
      int f = tid * 2 + j;
      int row = f >> 2;
      int kq = f & 3;
      float4 av = *(const float4*)&z[(m0 + row) * DM_ + k0 + kq * 4];
      As[kq * 4 + 0][row] = av.x; As[kq * 4 + 1][row] = av.y;
      As[kq * 4 + 2][row] = av.z; As[kq * 4 + 3][row] = av.w;
      float4 bv = *(const float4*)&Wo[(n0 + row) * DM_ + k0 + kq * 4];
      Bs[kq * 4 + 0][row] = bv.x; Bs[kq * 4 + 1][row] = bv.y;
      Bs[kq * 4 + 2][row] = bv.z; Bs[kq * 4 + 3][row] = bv.w;
    }
    __syncthreads();
#pragma unroll
    for (int kk = 0; kk < 16; ++kk) {
      float a[8], b[8];
      *(float4*)&a[0] = *(float4*)&As[kk][ty * 4];
      *(float4*)&a[4] = *(float4*)&As[kk][64 + ty * 4];
      *(float4*)&b[0] = *(float4*)&Bs[kk][tx * 4];
      *(float4*)&b[4] = *(float4*)&Bs[kk][64 + tx * 4];
#pragma unroll
      for (int i = 0; i < 8; ++i)
#pragma unroll
        for (int j = 0; j < 8; ++j) c[i][j] += a[i] * b[j];
    }
    __syncthreads();
  }
#pragma unroll
  for (int i = 0; i < 8; ++i) {
    int m = m0 + ((i < 4) ? (ty * 4 + i) : (64 + ty * 4 + i - 4));
#pragma unroll
    for (int jh = 0; jh < 2; ++jh) {
      int n = n0 + jh * 64 + tx * 4;
      float4 vv = make_float4(c[i][jh * 4 + 0], c[i][jh * 4 + 1],
                              c[i][jh * 4 + 2], c[i][jh * 4 + 3]);
      *(float4*)&out[m * DM_ + n] = vv;
    }
  }
}

// ---------------- RoPE apply (in-place on q,k in (B,H,T,D)) ----------------
// grid: B*H*T*32/256 = 16384 ; each thread rotates one (d, d+32) pair
__global__ __launch_bounds__(256) void k_rope_apply(float* __restrict__ q,
                                                    float* __restrict__ k,
                                                    const float* __restrict__ cosT,
                                                    const float* __restrict__ sinT) {
  int idx = blockIdx.x * 256 + threadIdx.x;
  int row = idx >> 5;         // (b*H+h)*T + t
  int p = idx & 31;
  int t = row & (T_ - 1);
  float cv = cosT[t * 32 + p], sv = sinT[t * 32 + p];
  size_t base = (size_t)row * D_;
  float q1 = q[base + p], q2 = q[base + p + 32];
  q[base + p] = q1 * cv - q2 * sv;
  q[base + p + 32] = q2 * cv + q1 * sv;
  float k1 = k[base + p], k2 = k[base + p + 32];
  k[base + p] = k1 * cv - k2 * sv;
  k[base + p + 32] = k2 * cv + k1 * sv;
}

// ---------------- TTT scan: one block per (b,h), 4 waves ----------------
// lane l = feature index e/d (0..63); wave w owns rows t in {w, 4+w, 8+w, 12+w}
__global__ __launch_bounds__(256) void k_scan(const float* __restrict__ qg,
                                              const float* __restrict__ kg,
                                              const float* __restrict__ vg,
                                              const float* __restrict__ eta,
                                              const float* __restrict__ W0,
                                              const float* __restrict__ lnw_g,
                                              const float* __restrict__ lnb_g,
                                              float* __restrict__ zg,
                                              float* __restrict__ wf) {
  __shared__ float Wl[64][68];
  __shared__ float Ks[16][68], Qs[16][68], Vs[16][68];
  __shared__ float Ue[16][64];   // for corr (stride-1 lane reads)
  __shared__ float UeT[64][20];  // for W update (broadcast float4 reads)
  __shared__ float Ss[16][16];
  __shared__ float Es[16];
  int bh = blockIdx.x;
  int b = bh >> 4, h = bh & 15;
  int tid = threadIdx.x;
  int w = tid >> 6, l = tid & 63;

  for (int idx = tid; idx < 4096; idx += 256)
    Wl[idx >> 6][idx & 63] = W0[bh * 4096 + idx];
  float lw = lnw_g[h * 64 + l];
  float lb = lnb_g[h * 64 + l];
  const float* kb = kg + (size_t)bh * (T_ * D_);
  const float* qb = qg + (size_t)bh * (T_ * D_);
  const float* vb = vg + (size_t)bh * (T_ * D_);

  for (int c = 0; c < NC_; ++c) {
    __syncthreads();  // prev chunk done with Ks/Qs/Vs; W writes visible
    {
      int r = tid >> 4, col = (tid & 15) * 4;
      int goff = c * (BT_ * D_) + r * D_ + col;
      *(float4*)&Ks[r][col] = *(const float4*)&kb[goff];
      *(float4*)&Qs[r][col] = *(const float4*)&qb[goff];
      *(float4*)&Vs[r][col] = *(const float4*)&vb[goff];
      if (tid < 16) Es[tid] = eta[b * T_ + c * BT_ + tid];
    }
    __syncthreads();

    // phase 1: tK = K@W^T and qd = Q@W^T (per-lane column e=l), LN fwd+bwd, Ue, S
    float tk[4], qd[4];
    tk[0] = tk[1] = tk[2] = tk[3] = 0.f;
    qd[0] = qd[1] = qd[2] = qd[3] = 0.f;
#pragma unroll
    for (int d4 = 0; d4 < 16; ++d4) {
      float4 wv = *(float4*)&Wl[l][d4 * 4];
#pragma unroll
      for (int i = 0; i < 4; ++i) {
        int t = i * 4 + w;
        float4 kv = *(float4*)&Ks[t][d4 * 4];
        float4 qv = *(float4*)&Qs[t][d4 * 4];
        tk[i] += wv.x * kv.x + wv.y * kv.y + wv.z * kv.z + wv.w * kv.w;
        qd[i] += wv.x * qv.x + wv.y * qv.y + wv.z * qv.z + wv.w * qv.w;
      }
    }
#pragma unroll
    for (int i = 0; i < 4; ++i) {
      int t = i * 4 + w;
      float s1 = wredsum(tk[i]);
      float s2 = wredsum(tk[i] * tk[i]);
      float mu = s1 * (1.f / 64.f);
      float var = s2 * (1.f / 64.f) - mu * mu;
      float inv = rsqrtf(var + 1e-5f);
      float xhat = (tk[i] - mu) * inv;
      float ln = xhat * lw + lb;
      float g = 0.125f * (Ks[t][l] + ln - Vs[t][l]);   // (2/BT)*(K + LN(tK) - V)
      float dxh = g * lw;
      float m1 = wredsum(dxh) * (1.f / 64.f);
      float m2 = wredsum(dxh * xhat) * (1.f / 64.f);
      float u = (dxh - m1 - xhat * m2) * inv;
      float ue = u * Es[t];
      Ue[t][l] = ue;
      UeT[l][t] = ue;
    }
    {  // S[t][s] = Q[t]·K[s]
      int t = (l >> 4) * 4 + w;
      int s = l & 15;
      float acc = 0.f;
#pragma unroll
      for (int d4 = 0; d4 < 16; ++d4) {
        float4 qv = *(float4*)&Qs[t][d4 * 4];
        float4 kv = *(float4*)&Ks[s][d4 * 4];
        acc += qv.x * kv.x + qv.y * kv.y + qv.z * kv.z + qv.w * kv.w;
      }
      Ss[t][s] = acc;
    }
    __syncthreads();

    // phase 2: corr (strict lower mask), TQ, LN, z
#pragma unroll
    for (int i = 0; i < 4; ++i) {
      int t = i * 4 + w;
      float corr = 0.f;
      for (int s = 0; s < t; ++s) corr += Ss[t][s] * Ue[s][l];
      float tq = qd[i] - corr;
      float s1 = wredsum(tq);
      float s2 = wredsum(tq * tq);
      float mu = s1 * (1.f / 64.f);
      float var = s2 * (1.f / 64.f) - mu * mu;
      float inv = rsqrtf(var + 1e-5f);
      float xhat = (tq - mu) * inv;
      float zv = Qs[t][l] + xhat * lw + lb;
      zg[((size_t)(b * T_ + c * BT_ + t)) * DM_ + h * 64 + l] = zv;
    }

    // phase 3: W -= Ue^T @ K  (wave w owns rows w*16..w*16+15; no extra barrier needed:
    // phase 2 doesn't read Wl, and Ue/UeT were complete at the phase-1 barrier)
    {
      float kc[16];
#pragma unroll
      for (int t = 0; t < 16; ++t) kc[t] = Ks[t][l];
#pragma unroll
      for (int ii = 0; ii < 16; ++ii) {
        int i = w * 16 + ii;
        float4 u0 = *(float4*)&UeT[i][0];
        float4 u1 = *(float4*)&UeT[i][4];
        float4 u2 = *(float4*)&UeT[i][8];
        float4 u3 = *(float4*)&UeT[i][12];
        float acc = u0.x * kc[0] + u0.y * kc[1] + u0.z * kc[2] + u0.w * kc[3]
                  + u1.x * kc[4] + u1.y * kc[5] + u1.z * kc[6] + u1.w * kc[7]
                  + u2.x * kc[8] + u2.y * kc[9] + u2.z * kc[10] + u2.w * kc[11]
                  + u3.x * kc[12] + u3.y * kc[13] + u3.z * kc[14] + u3.w * kc[15];
        Wl[i][l] -= acc;
      }
    }
  }
  __syncthreads();
  for (int idx = tid; idx < 4096; idx += 256)
    wf[bh * 4096 + idx] = Wl[idx >> 6][idx & 63];
}

extern "C" void kernel_launch(void* const* d_in, const int* in_sizes, int n_in,
                              void* d_out, int out_size, void* d_ws, size_t ws_size,
                              hipStream_t stream) {
  const float* x   = (const float*)d_in[0];
  const float* W0  = (const float*)d_in[1];
  const float* Wq  = (const float*)d_in[2];
  const float* Wk  = (const float*)d_in[3];
  const float* Wv  = (const float*)d_in[4];
  const float* Wo  = (const float*)d_in[5];
  const float* Wlr = (const float*)d_in[6];
  const float* lnw = (const float*)d_in[7];
  const float* lnb = (const float*)d_in[8];
  float* out = (float*)d_out;
  float* ws = (float*)d_ws;

  float* q    = ws;                 // 8,388,608 floats (B,H,T,D)
  float* k    = ws + 8388608;       // 8,388,608
  float* v    = ws + 16777216;      // 8,388,608
  float* z    = ws + 25165824;      // 8,388,608 (B,T,DM)
  float* eta  = ws + 33554432;      // 8192
  float* cosT = ws + 33562624;      // 65536
  float* sinT = ws + 33628160;      // 65536
  float* wf   = out + 8388608;      // second output: final W state

  hipLaunchKernelGGL(k_rope_table, dim3(256), dim3(256), 0, stream, cosT, sinT);
  hipLaunchKernelGGL(k_eta, dim3(2048), dim3(256), 0, stream, x, Wlr, eta);
  hipLaunchKernelGGL(k_gemm_qkv, dim3(64, 24), dim3(256), 0, stream, x, Wq, Wk, Wv, q, k, v);
  hipLaunchKernelGGL(k_rope_apply, dim3(16384), dim3(256), 0, stream, q, k, cosT, sinT);
  hipLaunchKernelGGL(k_scan, dim3(64), dim3(256), 0, stream, q, k, v, eta, W0, lnw, lnb, z, wf);
  hipLaunchKernelGGL(k_gemm_out, dim3(64, 8), dim3(256), 0, stream, z, Wo, out);
}

// Round 3
// 1007.452 us; speedup vs baseline: 2.0157x; 2.0157x over previous
//
#include <hip/hip_runtime.h>
#include <math.h>

#define B_ 4
#define T_ 2048
#define DM_ 1024
#define H_ 16
#define D_ 64
#define BT_ 16
#define NC_ 128

typedef _Float16 half8 __attribute__((ext_vector_type(8)));
typedef float f32x4 __attribute__((ext_vector_type(4)));

// ---- fast wave64 all-reduce sum: DPP prefix + row_bcast + readlane ----
template <int CTRL>
__device__ __forceinline__ float dppadd(float x) {
  return x + __int_as_float(__builtin_amdgcn_update_dpp(0, __float_as_int(x), CTRL, 0xf, 0xf, true));
}
__device__ __forceinline__ float wrs(float v) {
  v = dppadd<0x111>(v);  // row_shr:1
  v = dppadd<0x112>(v);  // row_shr:2
  v = dppadd<0x114>(v);  // row_shr:4
  v = dppadd<0x118>(v);  // row_shr:8  -> lane15 of each row16 has row sum
  v = dppadd<0x142>(v);  // row_bcast:15
  v = dppadd<0x143>(v);  // row_bcast:31 -> lane63 has full sum
  return __int_as_float(__builtin_amdgcn_readlane(__float_as_int(v), 63));
}

// ---------------- RoPE tables: cos/sin (T x 32) ----------------
__global__ void k_rope_table(float* __restrict__ cosT, float* __restrict__ sinT) {
  int idx = blockIdx.x * blockDim.x + threadIdx.x;
  if (idx >= T_ * 32) return;
  int t = idx >> 5, i = idx & 31;
  float inv = powf(10000.0f, -((float)(2 * i)) / 64.0f);
  float f = (float)t * inv;
  cosT[idx] = cosf(f);
  sinT[idx] = sinf(f);
}

// ---------------- eta = 0.01*sigmoid(x @ Wlr^T) ----------------
__global__ __launch_bounds__(256) void k_eta(const float* __restrict__ x,
                                             const float* __restrict__ Wlr,
                                             float* __restrict__ eta) {
  int w = threadIdx.x >> 6, l = threadIdx.x & 63;
  int row = blockIdx.x * 4 + w;
  const float* xr = x + (size_t)row * DM_;
  float s = 0.f;
#pragma unroll
  for (int j = 0; j < DM_ / 64; ++j) s += xr[j * 64 + l] * Wlr[j * 64 + l];
  s = wrs(s);
  if (l == 0) eta[row] = 0.01f / (1.0f + expf(-s));
}

// ---------------- fp32 -> fp16 conversion: x and Wq/Wk/Wv/Wo ----------------
__global__ __launch_bounds__(256) void k_cvt(const float* __restrict__ x,
                                             const float* __restrict__ Wq,
                                             const float* __restrict__ Wk,
                                             const float* __restrict__ Wv,
                                             const float* __restrict__ Wo,
                                             _Float16* __restrict__ xh,
                                             _Float16* __restrict__ wh) {
  int gid = blockIdx.x * 256 + threadIdx.x;
  const float* src;
  _Float16* dst;
  size_t off;
  if (gid < 1048576) {
    src = x; dst = xh; off = (size_t)gid * 8;
  } else {
    int j = gid - 1048576;
    int sel = j >> 17, jj = j & 131071;
    src = (sel == 0) ? Wq : (sel == 1) ? Wk : (sel == 2) ? Wv : Wo;
    dst = wh + (size_t)sel * 1048576;
    off = (size_t)jj * 8;
  }
  float4 a = *(const float4*)&src[off];
  float4 b = *(const float4*)&src[off + 4];
  half8 h;
  h[0] = (_Float16)a.x; h[1] = (_Float16)a.y; h[2] = (_Float16)a.z; h[3] = (_Float16)a.w;
  h[4] = (_Float16)b.x; h[5] = (_Float16)b.y; h[6] = (_Float16)b.z; h[7] = (_Float16)b.w;
  *(half8*)&dst[off] = h;
}

// ---------------- MFMA f16 GEMM helpers ----------------
// LDS tile: 128 rows x 64 halves, stored as 8 slots of 16B per row,
// slot swizzled: sw = slot ^ (row&7)  (T2-style, conflict-free frag reads)

// QKV fused: A = xh (8192x1024), B = wh[mat] (1024x1024 rowmajor = W),
// C[m][n] = sum_k A[m][k]*W[n][k]; scatter to (B,H,T,D) fp32.
__global__ __launch_bounds__(256) void k_gemm_qkv_h(const _Float16* __restrict__ xh,
                                                    const _Float16* __restrict__ wh,
                                                    float* __restrict__ qo,
                                                    float* __restrict__ ko,
                                                    float* __restrict__ vo) {
  __shared__ __align__(16) _Float16 As[128 * 64];
  __shared__ __align__(16) _Float16 Bs[128 * 64];
  int tid = threadIdx.x;
  int m0 = blockIdx.x * 128;
  int by = blockIdx.y;
  int mat = by >> 3;
  int n0 = (by & 7) * 128;
  const _Float16* Bsrc = wh + (size_t)mat * 1048576;
  float* op = (mat == 0) ? qo : (mat == 1) ? ko : vo;
  int wid = tid >> 6, l = tid & 63;
  int m0w = (wid >> 1) * 64, n0w = (wid & 1) * 64;
  int l15 = l & 15, l4 = l >> 4;

  f32x4 acc[4][4];
#pragma unroll
  for (int i = 0; i < 4; ++i)
#pragma unroll
    for (int j = 0; j < 4; ++j) acc[i][j] = (f32x4){0.f, 0.f, 0.f, 0.f};

  int lrow = tid >> 1;          // 0..127
  int lsb = (tid & 1) * 4;      // slot base
  uint4 ar[4], br[4];
#pragma unroll
  for (int j = 0; j < 4; ++j) {
    ar[j] = *(const uint4*)(xh + (size_t)(m0 + lrow) * 1024 + (lsb + j) * 8);
    br[j] = *(const uint4*)(Bsrc + (size_t)(n0 + lrow) * 1024 + (lsb + j) * 8);
  }

  for (int k0 = 0; k0 < 1024; k0 += 64) {
    __syncthreads();
#pragma unroll
    for (int j = 0; j < 4; ++j) {
      int sw = (lsb + j) ^ (lrow & 7);
      *(uint4*)((char*)As + lrow * 128 + sw * 16) = ar[j];
      *(uint4*)((char*)Bs + lrow * 128 + sw * 16) = br[j];
    }
    __syncthreads();
    if (k0 + 64 < 1024) {
#pragma unroll
      for (int j = 0; j < 4; ++j) {
        ar[j] = *(const uint4*)(xh + (size_t)(m0 + lrow) * 1024 + k0 + 64 + (lsb + j) * 8);
        br[j] = *(const uint4*)(Bsrc + (size_t)(n0 + lrow) * 1024 + k0 + 64 + (lsb + j) * 8);
      }
    }
#pragma unroll
    for (int kk = 0; kk < 2; ++kk) {
      half8 a[4], b[4];
#pragma unroll
      for (int mi = 0; mi < 4; ++mi) {
        int row = m0w + mi * 16 + l15;
        int sw = (kk * 4 + l4) ^ (row & 7);
        a[mi] = *(half8*)((char*)As + row * 128 + sw * 16);
      }
#pragma unroll
      for (int ni = 0; ni < 4; ++ni) {
        int row = n0w + ni * 16 + l15;
        int sw = (kk * 4 + l4) ^ (row & 7);
        b[ni] = *(half8*)((char*)Bs + row * 128 + sw * 16);
      }
#pragma unroll
      for (int mi = 0; mi < 4; ++mi)
#pragma unroll
        for (int ni = 0; ni < 4; ++ni)
          acc[mi][ni] = __builtin_amdgcn_mfma_f32_16x16x32_f16(a[mi], b[ni], acc[mi][ni], 0, 0, 0);
    }
  }
  // epilogue: D row = (l>>4)*4 + r, col = l&15 ; scatter (B,H,T,D)
#pragma unroll
  for (int mi = 0; mi < 4; ++mi)
#pragma unroll
    for (int ni = 0; ni < 4; ++ni)
#pragma unroll
      for (int r = 0; r < 4; ++r) {
        int m = m0 + m0w + mi * 16 + l4 * 4 + r;
        int n = n0 + n0w + ni * 16 + l15;
        int bb = m >> 11, t = m & (T_ - 1);
        int h = n >> 6, d = n & 63;
        op[(((size_t)bb * H_ + h) * T_ + t) * D_ + d] = acc[mi][ni][r];
      }
}

// out = zh @ Wo^T (fp32 out, 8192x1024x1024)
__global__ __launch_bounds__(256) void k_gemm_out_h(const _Float16* __restrict__ zh,
                                                    const _Float16* __restrict__ woh,
                                                    float* __restrict__ out) {
  __shared__ __align__(16) _Float16 As[128 * 64];
  __shared__ __align__(16) _Float16 Bs[128 * 64];
  int tid = threadIdx.x;
  int m0 = blockIdx.x * 128;
  int n0 = blockIdx.y * 128;
  int wid = tid >> 6, l = tid & 63;
  int m0w = (wid >> 1) * 64, n0w = (wid & 1) * 64;
  int l15 = l & 15, l4 = l >> 4;

  f32x4 acc[4][4];
#pragma unroll
  for (int i = 0; i < 4; ++i)
#pragma unroll
    for (int j = 0; j < 4; ++j) acc[i][j] = (f32x4){0.f, 0.f, 0.f, 0.f};

  int lrow = tid >> 1;
  int lsb = (tid & 1) * 4;
  uint4 ar[4], br[4];
#pragma unroll
  for (int j = 0; j < 4; ++j) {
    ar[j] = *(const uint4*)(zh + (size_t)(m0 + lrow) * 1024 + (lsb + j) * 8);
    br[j] = *(const uint4*)(woh + (size_t)(n0 + lrow) * 1024 + (lsb + j) * 8);
  }

  for (int k0 = 0; k0 < 1024; k0 += 64) {
    __syncthreads();
#pragma unroll
    for (int j = 0; j < 4; ++j) {
      int sw = (lsb + j) ^ (lrow & 7);
      *(uint4*)((char*)As + lrow * 128 + sw * 16) = ar[j];
      *(uint4*)((char*)Bs + lrow * 128 + sw * 16) = br[j];
    }
    __syncthreads();
    if (k0 + 64 < 1024) {
#pragma unroll
      for (int j = 0; j < 4; ++j) {
        ar[j] = *(const uint4*)(zh + (size_t)(m0 + lrow) * 1024 + k0 + 64 + (lsb + j) * 8);
        br[j] = *(const uint4*)(woh + (size_t)(n0 + lrow) * 1024 + k0 + 64 + (lsb + j) * 8);
      }
    }
#pragma unroll
    for (int kk = 0; kk < 2; ++kk) {
      half8 a[4], b[4];
#pragma unroll
      for (int mi = 0; mi < 4; ++mi) {
        int row = m0w + mi * 16 + l15;
        int sw = (kk * 4 + l4) ^ (row & 7);
        a[mi] = *(half8*)((char*)As + row * 128 + sw * 16);
      }
#pragma unroll
      for (int ni = 0; ni < 4; ++ni) {
        int row = n0w + ni * 16 + l15;
        int sw = (kk * 4 + l4) ^ (row & 7);
        b[ni] = *(half8*)((char*)Bs + row * 128 + sw * 16);
      }
#pragma unroll
      for (int mi = 0; mi < 4; ++mi)
#pragma unroll
        for (int ni = 0; ni < 4; ++ni)
          acc[mi][ni] = __builtin_amdgcn_mfma_f32_16x16x32_f16(a[mi], b[ni], acc[mi][ni], 0, 0, 0);
    }
  }
#pragma unroll
  for (int mi = 0; mi < 4; ++mi)
#pragma unroll
    for (int ni = 0; ni < 4; ++ni)
#pragma unroll
      for (int r = 0; r < 4; ++r) {
        int m = m0 + m0w + mi * 16 + l4 * 4 + r;
        int n = n0 + n0w + ni * 16 + l15;
        out[(size_t)m * DM_ + n] = acc[mi][ni][r];
      }
}

// ---------------- RoPE apply (in-place, fp32 q,k) ----------------
__global__ __launch_bounds__(256) void k_rope_apply(float* __restrict__ q,
                                                    float* __restrict__ k,
                                                    const float* __restrict__ cosT,
                                                    const float* __restrict__ sinT) {
  int idx = blockIdx.x * 256 + threadIdx.x;
  int row = idx >> 5;
  int p = idx & 31;
  int t = row & (T_ - 1);
  float cv = cosT[t * 32 + p], sv = sinT[t * 32 + p];
  size_t base = (size_t)row * D_;
  float q1 = q[base + p], q2 = q[base + p + 32];
  q[base + p] = q1 * cv - q2 * sv;
  q[base + p + 32] = q2 * cv + q1 * sv;
  float k1 = k[base + p], k2 = k[base + p + 32];
  k[base + p] = k1 * cv - k2 * sv;
  k[base + p + 32] = k2 * cv + k1 * sv;
}

// ---------------- TTT scan: 1 block/(b,h), 8 waves, DPP LN, dbuf prefetch ----------------
// lane l = feature (0..63); wave w owns rows t in {w, 8+w}
__global__ __launch_bounds__(512) void k_scan(const float* __restrict__ qg,
                                              const float* __restrict__ kg,
                                              const float* __restrict__ vg,
                                              const float* __restrict__ etag,
                                              const float* __restrict__ W0,
                                              const float* __restrict__ lnw_g,
                                              const float* __restrict__ lnb_g,
                                              _Float16* __restrict__ zg,
                                              float* __restrict__ wf) {
  __shared__ __align__(16) float Wl[64][68];
  __shared__ __align__(16) float Ks[2][16][68], Qs[2][16][68], Vs[2][16][68];
  __shared__ __align__(16) float Ue[16][64];
  __shared__ __align__(16) float UeT[64][20];
  __shared__ float Ss[16][16];
  __shared__ float Es[2][16];
  int bh = blockIdx.x, b = bh >> 4, h = bh & 15;
  int tid = threadIdx.x, w = tid >> 6, l = tid & 63;

  for (int idx = tid; idx < 4096; idx += 512)
    Wl[idx >> 6][idx & 63] = W0[(size_t)bh * 4096 + idx];
  float lw = lnw_g[h * 64 + l];
  float lb = lnb_g[h * 64 + l];
  const float* kb = kg + (size_t)bh * (T_ * D_);
  const float* qb = qg + (size_t)bh * (T_ * D_);
  const float* vb = vg + (size_t)bh * (T_ * D_);

  // prologue: stage chunk 0
  if (tid < 256) {
    int r = tid >> 4, c4 = (tid & 15) * 4;
    *(float4*)&Ks[0][r][c4] = *(const float4*)&kb[r * 64 + c4];
    *(float4*)&Vs[0][r][c4] = *(const float4*)&vb[r * 64 + c4];
    if (tid < 16) Es[0][tid] = etag[b * T_ + tid];
  } else {
    int t2 = tid - 256;
    int r = t2 >> 4, c4 = (t2 & 15) * 4;
    *(float4*)&Qs[0][r][c4] = *(const float4*)&qb[r * 64 + c4];
  }

  for (int c = 0; c < NC_; ++c) {
    int cur = c & 1, nxt = cur ^ 1;
    __syncthreads();  // B1: buf[cur] + W updates visible
    bool pf = (c + 1 < NC_);
    float4 fk, fv, fq;
    float fe = 0.f;
    if (pf) {  // issue next-chunk loads (latency hidden under compute)
      int goff = (c + 1) * (BT_ * D_);
      if (tid < 256) {
        int r = tid >> 4, c4 = (tid & 15) * 4;
        fk = *(const float4*)&kb[goff + r * 64 + c4];
        fv = *(const float4*)&vb[goff + r * 64 + c4];
        if (tid < 16) fe = etag[b * T_ + (c + 1) * BT_ + tid];
      } else {
        int t2 = tid - 256;
        int r = t2 >> 4, c4 = (t2 & 15) * 4;
        fq = *(const float4*)&qb[goff + r * 64 + c4];
      }
    }

    // ---- phase 1: tK/qd dots, LN fwd+bwd (DPP), Ue, masked S ----
    float tk[2], qd[2];
    tk[0] = tk[1] = 0.f;
    qd[0] = qd[1] = 0.f;
#pragma unroll
    for (int d4 = 0; d4 < 16; ++d4) {
      float4 wv = *(float4*)&Wl[l][d4 * 4];
#pragma unroll
      for (int i = 0; i < 2; ++i) {
        int t = i * 8 + w;
        float4 kv = *(float4*)&Ks[cur][t][d4 * 4];
        float4 qv = *(float4*)&Qs[cur][t][d4 * 4];
        tk[i] += wv.x * kv.x + wv.y * kv.y + wv.z * kv.z + wv.w * kv.w;
        qd[i] += wv.x * qv.x + wv.y * qv.y + wv.z * qv.z + wv.w * qv.w;
      }
    }
#pragma unroll
    for (int i = 0; i < 2; ++i) {
      int t = i * 8 + w;
      float s1 = wrs(tk[i]);
      float s2 = wrs(tk[i] * tk[i]);
      float mu = s1 * 0.015625f;
      float var = s2 * 0.015625f - mu * mu;
      float inv = rsqrtf(var + 1e-5f);
      float xhat = (tk[i] - mu) * inv;
      float ln = xhat * lw + lb;
      float g = 0.125f * (Ks[cur][t][l] + ln - Vs[cur][t][l]);
      float dxh = g * lw;
      float m1 = wrs(dxh) * 0.015625f;
      float m2 = wrs(dxh * xhat) * 0.015625f;
      float ue = (dxh - m1 - xhat * m2) * inv * Es[cur][t];
      Ue[t][l] = ue;
      UeT[l][t] = ue;
    }
    {  // S[t][s] = Q[t].K[s], masked at write (s<t strict lower)
      int s = l & 15;
      int t = 8 * ((l >> 4) & 1) + w;
      float acc = 0.f;
#pragma unroll
      for (int d4 = 0; d4 < 16; ++d4) {
        float4 qv = *(float4*)&Qs[cur][t][d4 * 4];
        float4 kv = *(float4*)&Ks[cur][s][d4 * 4];
        acc += qv.x * kv.x + qv.y * kv.y + qv.z * kv.z + qv.w * kv.w;
      }
      Ss[t][s] = (s < t) ? acc : 0.f;
    }
    __syncthreads();  // B2: Ue/S visible

    // ---- phase 2: corr (unrolled masked), LN, z (fp16) ----
#pragma unroll
    for (int i = 0; i < 2; ++i) {
      int t = i * 8 + w;
      float corr = 0.f;
#pragma unroll
      for (int s = 0; s < 16; ++s) corr += Ss[t][s] * Ue[s][l];
      float tq = qd[i] - corr;
      float s1 = wrs(tq);
      float s2 = wrs(tq * tq);
      float mu = s1 * 0.015625f;
      float var = s2 * 0.015625f - mu * mu;
      float inv = rsqrtf(var + 1e-5f);
      float zv = Qs[cur][t][l] + ((tq - mu) * inv) * lw + lb;
      zg[((size_t)(b * T_ + c * BT_ + t)) * DM_ + h * 64 + l] = (_Float16)zv;
    }

    // ---- phase 3: W -= Ue^T @ K (wave w owns rows w*8..w*8+7) ----
    {
      float kc[16];
#pragma unroll
      for (int t = 0; t < 16; ++t) kc[t] = Ks[cur][t][l];
#pragma unroll
      for (int ii = 0; ii < 8; ++ii) {
        int i = w * 8 + ii;
        float4 u0 = *(float4*)&UeT[i][0];
        float4 u1 = *(float4*)&UeT[i][4];
        float4 u2 = *(float4*)&UeT[i][8];
        float4 u3 = *(float4*)&UeT[i][12];
        float acc = u0.x * kc[0] + u0.y * kc[1] + u0.z * kc[2] + u0.w * kc[3]
                  + u1.x * kc[4] + u1.y * kc[5] + u1.z * kc[6] + u1.w * kc[7]
                  + u2.x * kc[8] + u2.y * kc[9] + u2.z * kc[10] + u2.w * kc[11]
                  + u3.x * kc[12] + u3.y * kc[13] + u3.z * kc[14] + u3.w * kc[15];
        Wl[i][l] -= acc;
      }
    }

    // ---- stage prefetched chunk into buf[nxt] (visible after next B1) ----
    if (pf) {
      if (tid < 256) {
        int r = tid >> 4, c4 = (tid & 15) * 4;
        *(float4*)&Ks[nxt][r][c4] = fk;
        *(float4*)&Vs[nxt][r][c4] = fv;
        if (tid < 16) Es[nxt][tid] = fe;
      } else {
        int t2 = tid - 256;
        int r = t2 >> 4, c4 = (t2 & 15) * 4;
        *(float4*)&Qs[nxt][r][c4] = fq;
      }
    }
  }
  __syncthreads();
  for (int idx = tid; idx < 4096; idx += 512)
    wf[(size_t)bh * 4096 + idx] = Wl[idx >> 6][idx & 63];
}

extern "C" void kernel_launch(void* const* d_in, const int* in_sizes, int n_in,
                              void* d_out, int out_size, void* d_ws, size_t ws_size,
                              hipStream_t stream) {
  const float* x   = (const float*)d_in[0];
  const float* W0  = (const float*)d_in[1];
  const float* Wq  = (const float*)d_in[2];
  const float* Wk  = (const float*)d_in[3];
  const float* Wv  = (const float*)d_in[4];
  const float* Wo  = (const float*)d_in[5];
  const float* Wlr = (const float*)d_in[6];
  const float* lnw = (const float*)d_in[7];
  const float* lnb = (const float*)d_in[8];
  float* out = (float*)d_out;
  float* ws = (float*)d_ws;

  float* q    = ws;                      // 8,388,608 f
  float* k    = q + 8388608;             // 8,388,608 f
  float* v    = k + 8388608;             // 8,388,608 f
  float* eta  = v + 8388608;             // 8192 f
  float* cosT = eta + 8192;              // 65536 f
  float* sinT = cosT + 65536;            // 65536 f
  _Float16* xh = (_Float16*)(sinT + 65536);  // 8,388,608 halves
  _Float16* wh = xh + 8388608;               // 4x 1,048,576 halves
  _Float16* zh = xh;                         // alias: xh dead after qkv GEMM
  float* wf = out + 8388608;             // output #2: final W

  hipLaunchKernelGGL(k_rope_table, dim3(256), dim3(256), 0, stream, cosT, sinT);
  hipLaunchKernelGGL(k_cvt, dim3(6144), dim3(256), 0, stream, x, Wq, Wk, Wv, Wo, xh, wh);
  hipLaunchKernelGGL(k_eta, dim3(2048), dim3(256), 0, stream, x, Wlr, eta);
  hipLaunchKernelGGL(k_gemm_qkv_h, dim3(64, 24), dim3(256), 0, stream, xh, wh, q, k, v);
  hipLaunchKernelGGL(k_rope_apply, dim3(16384), dim3(256), 0, stream, q, k, cosT, sinT);
  hipLaunchKernelGGL(k_scan, dim3(64), dim3(512), 0, stream, q, k, v, eta, W0, lnw, lnb, zh, wf);
  hipLaunchKernelGGL(k_gemm_out_h, dim3(64, 8), dim3(256), 0, stream, zh, wh + 3145728, out);
}

// Round 4
// 658.738 us; speedup vs baseline: 3.0827x; 1.5294x over previous
//
#include <hip/hip_runtime.h>
#include <math.h>

#define B_ 4
#define T_ 2048
#define DM_ 1024
#define H_ 16
#define D_ 64
#define BT_ 16
#define NC_ 128

typedef _Float16 half8 __attribute__((ext_vector_type(8)));
typedef _Float16 half4 __attribute__((ext_vector_type(4)));
typedef float f32x4 __attribute__((ext_vector_type(4)));

#define MFMA16 __builtin_amdgcn_mfma_f32_16x16x32_f16

// ---- fast wave64 all-reduce sum: DPP prefix + row_bcast + readlane ----
template <int CTRL>
__device__ __forceinline__ float dppadd(float x) {
  return x + __int_as_float(__builtin_amdgcn_update_dpp(0, __float_as_int(x), CTRL, 0xf, 0xf, true));
}
__device__ __forceinline__ float wrs(float v) {
  v = dppadd<0x111>(v);
  v = dppadd<0x112>(v);
  v = dppadd<0x114>(v);
  v = dppadd<0x118>(v);
  v = dppadd<0x142>(v);
  v = dppadd<0x143>(v);
  return __int_as_float(__builtin_amdgcn_readlane(__float_as_int(v), 63));
}

// byte offset into a [rows][64] f16 tile stored as 128B rows, 16B slots XOR-swizzled
__device__ __forceinline__ int sw128(int row, int slot) {
  return row * 128 + ((slot ^ (row & 7)) * 16);
}

// ---------------- RoPE tables: cos/sin (T x 32) ----------------
__global__ void k_rope_table(float* __restrict__ cosT, float* __restrict__ sinT) {
  int idx = blockIdx.x * blockDim.x + threadIdx.x;
  if (idx >= T_ * 32) return;
  int t = idx >> 5, i = idx & 31;
  float inv = powf(10000.0f, -((float)(2 * i)) / 64.0f);
  float f = (float)t * inv;
  cosT[idx] = cosf(f);
  sinT[idx] = sinf(f);
}

// ---------------- eta = 0.01*sigmoid(x @ Wlr^T) ----------------
__global__ __launch_bounds__(256) void k_eta(const float* __restrict__ x,
                                             const float* __restrict__ Wlr,
                                             float* __restrict__ eta) {
  int w = threadIdx.x >> 6, l = threadIdx.x & 63;
  int row = blockIdx.x * 4 + w;
  const float* xr = x + (size_t)row * DM_;
  float s = 0.f;
#pragma unroll
  for (int j = 0; j < DM_ / 64; ++j) s += xr[j * 64 + l] * Wlr[j * 64 + l];
  s = wrs(s);
  if (l == 0) eta[row] = 0.01f / (1.0f + expf(-s));
}

// ---------------- fp32 -> fp16 conversion: x and Wq/Wk/Wv/Wo ----------------
__global__ __launch_bounds__(256) void k_cvt(const float* __restrict__ x,
                                             const float* __restrict__ Wq,
                                             const float* __restrict__ Wk,
                                             const float* __restrict__ Wv,
                                             const float* __restrict__ Wo,
                                             _Float16* __restrict__ xh,
                                             _Float16* __restrict__ wh) {
  int gid = blockIdx.x * 256 + threadIdx.x;
  const float* src;
  _Float16* dst;
  size_t off;
  if (gid < 1048576) {
    src = x; dst = xh; off = (size_t)gid * 8;
  } else {
    int j = gid - 1048576;
    int sel = j >> 17, jj = j & 131071;
    src = (sel == 0) ? Wq : (sel == 1) ? Wk : (sel == 2) ? Wv : Wo;
    dst = wh + (size_t)sel * 1048576;
    off = (size_t)jj * 8;
  }
  float4 a = *(const float4*)&src[off];
  float4 b = *(const float4*)&src[off + 4];
  half8 h;
  h[0] = (_Float16)a.x; h[1] = (_Float16)a.y; h[2] = (_Float16)a.z; h[3] = (_Float16)a.w;
  h[4] = (_Float16)b.x; h[5] = (_Float16)b.y; h[6] = (_Float16)b.z; h[7] = (_Float16)b.w;
  *(half8*)&dst[off] = h;
}

// ---------------- QKV GEMM (f16 MFMA) with fused RoPE epilogue ----------------
__global__ __launch_bounds__(256) void k_gemm_qkv_h(const _Float16* __restrict__ xh,
                                                    const _Float16* __restrict__ wh,
                                                    const float* __restrict__ cosT,
                                                    const float* __restrict__ sinT,
                                                    float* __restrict__ qo,
                                                    float* __restrict__ ko,
                                                    float* __restrict__ vo) {
  __shared__ __align__(16) _Float16 As[128 * 64];
  __shared__ __align__(16) _Float16 Bs[128 * 64];
  int tid = threadIdx.x;
  int m0 = blockIdx.x * 128;
  int by = blockIdx.y;
  int mat = by >> 3;
  int n0 = (by & 7) * 128;
  const _Float16* Bsrc = wh + (size_t)mat * 1048576;
  float* op = (mat == 0) ? qo : (mat == 1) ? ko : vo;
  int wid = tid >> 6, l = tid & 63;
  int m0w = (wid >> 1) * 64, n0w = (wid & 1) * 64;
  int l15 = l & 15, l4 = l >> 4;

  f32x4 acc[4][4];
#pragma unroll
  for (int i = 0; i < 4; ++i)
#pragma unroll
    for (int j = 0; j < 4; ++j) acc[i][j] = (f32x4){0.f, 0.f, 0.f, 0.f};

  int lrow = tid >> 1;
  int lsb = (tid & 1) * 4;
  uint4 ar[4], br[4];
#pragma unroll
  for (int j = 0; j < 4; ++j) {
    ar[j] = *(const uint4*)(xh + (size_t)(m0 + lrow) * 1024 + (lsb + j) * 8);
    br[j] = *(const uint4*)(Bsrc + (size_t)(n0 + lrow) * 1024 + (lsb + j) * 8);
  }

  for (int k0 = 0; k0 < 1024; k0 += 64) {
    __syncthreads();
#pragma unroll
    for (int j = 0; j < 4; ++j) {
      int sw = (lsb + j) ^ (lrow & 7);
      *(uint4*)((char*)As + lrow * 128 + sw * 16) = ar[j];
      *(uint4*)((char*)Bs + lrow * 128 + sw * 16) = br[j];
    }
    __syncthreads();
    if (k0 + 64 < 1024) {
#pragma unroll
      for (int j = 0; j < 4; ++j) {
        ar[j] = *(const uint4*)(xh + (size_t)(m0 + lrow) * 1024 + k0 + 64 + (lsb + j) * 8);
        br[j] = *(const uint4*)(Bsrc + (size_t)(n0 + lrow) * 1024 + k0 + 64 + (lsb + j) * 8);
      }
    }
#pragma unroll
    for (int kk = 0; kk < 2; ++kk) {
      half8 a[4], b[4];
#pragma unroll
      for (int mi = 0; mi < 4; ++mi) {
        int row = m0w + mi * 16 + l15;
        int sw = (kk * 4 + l4) ^ (row & 7);
        a[mi] = *(half8*)((char*)As + row * 128 + sw * 16);
      }
#pragma unroll
      for (int ni = 0; ni < 4; ++ni) {
        int row = n0w + ni * 16 + l15;
        int sw = (kk * 4 + l4) ^ (row & 7);
        b[ni] = *(half8*)((char*)Bs + row * 128 + sw * 16);
      }
#pragma unroll
      for (int mi = 0; mi < 4; ++mi)
#pragma unroll
        for (int ni = 0; ni < 4; ++ni)
          acc[mi][ni] = MFMA16(a[mi], b[ni], acc[mi][ni], 0, 0, 0);
    }
  }
  // fused RoPE (q,k only): pair (d, d+32) = (ni, ni+2) in same lane
  if (mat < 2) {
#pragma unroll
    for (int mi = 0; mi < 4; ++mi)
#pragma unroll
      for (int r = 0; r < 4; ++r) {
        int m = m0 + m0w + mi * 16 + l4 * 4 + r;
        int t = m & (T_ - 1);
#pragma unroll
        for (int ni = 0; ni < 2; ++ni) {
          int d1 = ni * 16 + l15;  // < 32
          float cv = cosT[t * 32 + d1];
          float sv = sinT[t * 32 + d1];
          float x1 = acc[mi][ni][r], x2 = acc[mi][ni + 2][r];
          acc[mi][ni][r] = x1 * cv - x2 * sv;
          acc[mi][ni + 2][r] = x2 * cv + x1 * sv;
        }
      }
  }
  // scatter to (B,H,T,D)
#pragma unroll
  for (int mi = 0; mi < 4; ++mi)
#pragma unroll
    for (int ni = 0; ni < 4; ++ni)
#pragma unroll
      for (int r = 0; r < 4; ++r) {
        int m = m0 + m0w + mi * 16 + l4 * 4 + r;
        int n = n0 + n0w + ni * 16 + l15;
        int bb = m >> 11, t = m & (T_ - 1);
        int h = n >> 6, d = n & 63;
        op[(((size_t)bb * H_ + h) * T_ + t) * D_ + d] = acc[mi][ni][r];
      }
}

// ---------------- out = zh @ Wo^T ----------------
__global__ __launch_bounds__(256) void k_gemm_out_h(const _Float16* __restrict__ zh,
                                                    const _Float16* __restrict__ woh,
                                                    float* __restrict__ out) {
  __shared__ __align__(16) _Float16 As[128 * 64];
  __shared__ __align__(16) _Float16 Bs[128 * 64];
  int tid = threadIdx.x;
  int m0 = blockIdx.x * 128;
  int n0 = blockIdx.y * 128;
  int wid = tid >> 6, l = tid & 63;
  int m0w = (wid >> 1) * 64, n0w = (wid & 1) * 64;
  int l15 = l & 15, l4 = l >> 4;

  f32x4 acc[4][4];
#pragma unroll
  for (int i = 0; i < 4; ++i)
#pragma unroll
    for (int j = 0; j < 4; ++j) acc[i][j] = (f32x4){0.f, 0.f, 0.f, 0.f};

  int lrow = tid >> 1;
  int lsb = (tid & 1) * 4;
  uint4 ar[4], br[4];
#pragma unroll
  for (int j = 0; j < 4; ++j) {
    ar[j] = *(const uint4*)(zh + (size_t)(m0 + lrow) * 1024 + (lsb + j) * 8);
    br[j] = *(const uint4*)(woh + (size_t)(n0 + lrow) * 1024 + (lsb + j) * 8);
  }

  for (int k0 = 0; k0 < 1024; k0 += 64) {
    __syncthreads();
#pragma unroll
    for (int j = 0; j < 4; ++j) {
      int sw = (lsb + j) ^ (lrow & 7);
      *(uint4*)((char*)As + lrow * 128 + sw * 16) = ar[j];
      *(uint4*)((char*)Bs + lrow * 128 + sw * 16) = br[j];
    }
    __syncthreads();
    if (k0 + 64 < 1024) {
#pragma unroll
      for (int j = 0; j < 4; ++j) {
        ar[j] = *(const uint4*)(zh + (size_t)(m0 + lrow) * 1024 + k0 + 64 + (lsb + j) * 8);
        br[j] = *(const uint4*)(woh + (size_t)(n0 + lrow) * 1024 + k0 + 64 + (lsb + j) * 8);
      }
    }
#pragma unroll
    for (int kk = 0; kk < 2; ++kk) {
      half8 a[4], b[4];
#pragma unroll
      for (int mi = 0; mi < 4; ++mi) {
        int row = m0w + mi * 16 + l15;
        int sw = (kk * 4 + l4) ^ (row & 7);
        a[mi] = *(half8*)((char*)As + row * 128 + sw * 16);
      }
#pragma unroll
      for (int ni = 0; ni < 4; ++ni) {
        int row = n0w + ni * 16 + l15;
        int sw = (kk * 4 + l4) ^ (row & 7);
        b[ni] = *(half8*)((char*)Bs + row * 128 + sw * 16);
      }
#pragma unroll
      for (int mi = 0; mi < 4; ++mi)
#pragma unroll
        for (int ni = 0; ni < 4; ++ni)
          acc[mi][ni] = MFMA16(a[mi], b[ni], acc[mi][ni], 0, 0, 0);
    }
  }
#pragma unroll
  for (int mi = 0; mi < 4; ++mi)
#pragma unroll
    for (int ni = 0; ni < 4; ++ni)
#pragma unroll
      for (int r = 0; r < 4; ++r) {
        int m = m0 + m0w + mi * 16 + l4 * 4 + r;
        int n = n0 + n0w + ni * 16 + l15;
        out[(size_t)m * DM_ + n] = acc[mi][ni][r];
      }
}

// ---------------- TTT scan: MFMA-based, 1 block/(b,h), 8 waves ----------------
// W lives in f32 MFMA accumulators: wave w owns tiles (ti=w>>1, tj0=(w&1)*2, tj0+1).
// Per step: A: tK=K@W^T (waves0-3), qd=Q@W^T (4-7), S=Q@K^T (wave4) via MFMA
//           B: LN fwd+bwd (DPP) -> ue -> UeT_h
//           C: TQ = qd - S@Ue (MFMA, signs folded), W-update MFMA, Wh refresh
//           D: LN(TQ) -> z; stage next chunk
__global__ __launch_bounds__(512) void k_scan(const float* __restrict__ qg,
                                              const float* __restrict__ kg,
                                              const float* __restrict__ vg,
                                              const float* __restrict__ etag,
                                              const float* __restrict__ W0,
                                              const float* __restrict__ lnw_g,
                                              const float* __restrict__ lnb_g,
                                              _Float16* __restrict__ zg,
                                              float* __restrict__ wf) {
  __shared__ __align__(16) float Ksf[2][16][68], Qsf[2][16][68], Vsf[2][16][68];
  __shared__ __align__(16) _Float16 Ks_h[2][1024], Qs_h[2][1024];  // 16 x 128B swizzled rows
  __shared__ __align__(16) _Float16 KT_h[2][64 * 24];              // [d][t], stride 24, = -K
  __shared__ __align__(16) _Float16 Wh[64 * 64];                   // [e][d] swizzled, fp16 W
  __shared__ __align__(16) float tKs[16][68], tqs[16][68];
  __shared__ __align__(16) _Float16 Ss_h[16 * 24];                 // [t][s], = -S masked
  __shared__ __align__(16) _Float16 UeT_h[64 * 24];                // [e][t], = +ue
  __shared__ float Es[2][16];

  int bh = blockIdx.x, b = bh >> 4, h = bh & 15;
  int tid = threadIdx.x, w = tid >> 6, l = tid & 63;
  int l15 = l & 15, g = l >> 4;
  int ti = w >> 1, tj0 = (w & 1) * 2, tj1 = tj0 + 1;
  int d0 = tj0 * 16 + l15, d1 = tj1 * 16 + l15;

  float lw = lnw_g[h * 64 + l];
  float lb = lnb_g[h * 64 + l];
  const float* kb = kg + (size_t)bh * (T_ * D_);
  const float* qb = qg + (size_t)bh * (T_ * D_);
  const float* vb = vg + (size_t)bh * (T_ * D_);

  // ---- W0 -> accumulators + initial Wh ----
  const float* w0p = W0 + (size_t)bh * 4096;
  f32x4 accW0, accW1;
#pragma unroll
  for (int r = 0; r < 4; ++r) {
    int e = ti * 16 + g * 4 + r;
    accW0[r] = w0p[e * 64 + d0];
    accW1[r] = w0p[e * 64 + d1];
  }
#pragma unroll
  for (int r = 0; r < 4; ++r) {
    int e = ti * 16 + g * 4 + r;
    *(_Float16*)((char*)Wh + sw128(e, d0 >> 3) + (d0 & 7) * 2) = (_Float16)accW0[r];
    *(_Float16*)((char*)Wh + sw128(e, d1 >> 3) + (d1 & 7) * 2) = (_Float16)accW1[r];
  }

  // ---- stage chunk 0 ----
  {
    if (tid < 256) {
      int r = tid >> 4, c4 = (tid & 15) * 4;
      float4 fk = *(const float4*)&kb[r * 64 + c4];
      float4 fv = *(const float4*)&vb[r * 64 + c4];
      *(float4*)&Ksf[0][r][c4] = fk;
      *(float4*)&Vsf[0][r][c4] = fv;
      half4 hk = {(_Float16)fk.x, (_Float16)fk.y, (_Float16)fk.z, (_Float16)fk.w};
      *(half4*)((char*)Ks_h[0] + sw128(r, c4 >> 3) + (c4 & 7) * 2) = hk;
      const float* fkp = &fk.x;
#pragma unroll
      for (int i = 0; i < 4; ++i)
        *(_Float16*)((char*)KT_h[0] + (c4 + i) * 48 + r * 2) = (_Float16)(-fkp[i]);
      if (tid < 16) Es[0][tid] = etag[b * T_ + tid];
    } else {
      int t2 = tid - 256;
      int r = t2 >> 4, c4 = (t2 & 15) * 4;
      float4 fq = *(const float4*)&qb[r * 64 + c4];
      *(float4*)&Qsf[0][r][c4] = fq;
      half4 hq = {(_Float16)fq.x, (_Float16)fq.y, (_Float16)fq.z, (_Float16)fq.w};
      *(half4*)((char*)Qs_h[0] + sw128(r, c4 >> 3) + (c4 & 7) * 2) = hq;
    }
  }

  const half8 Z8 = {0, 0, 0, 0, 0, 0, 0, 0};

  for (int c = 0; c < NC_; ++c) {
    int cur = c & 1, nxt = cur ^ 1;
    __syncthreads();  // B1: buf[cur] + Wh visible

    bool pf = (c + 1 < NC_);
    float4 fk, fv, fq;
    float fe = 0.f;
    if (pf) {
      int goff = (c + 1) * (BT_ * D_);
      if (tid < 256) {
        int r = tid >> 4, c4 = (tid & 15) * 4;
        fk = *(const float4*)&kb[goff + r * 64 + c4];
        fv = *(const float4*)&vb[goff + r * 64 + c4];
        if (tid < 16) fe = etag[b * T_ + (c + 1) * BT_ + tid];
      } else {
        int t2 = tid - 256;
        int r = t2 >> 4, c4 = (t2 & 15) * 4;
        fq = *(const float4*)&qb[goff + r * 64 + c4];
      }
    }

    // ---- Phase A: MFMA tK / qd / S ----
    int j = w & 3;
    const _Float16* Asrc = (w < 4) ? Ks_h[cur] : Qs_h[cur];
    half8 a0 = *(const half8*)((const char*)Asrc + sw128(l15, g));
    half8 a1 = *(const half8*)((const char*)Asrc + sw128(l15, 4 + g));
    int ecol = j * 16 + l15;
    half8 b0 = *(const half8*)((const char*)Wh + sw128(ecol, g));
    half8 b1 = *(const half8*)((const char*)Wh + sw128(ecol, 4 + g));
    f32x4 accA = (f32x4){0.f, 0.f, 0.f, 0.f};
    accA = MFMA16(a0, b0, accA, 0, 0, 0);
    accA = MFMA16(a1, b1, accA, 0, 0, 0);
    if (w < 4) {
#pragma unroll
      for (int r = 0; r < 4; ++r) tKs[g * 4 + r][j * 16 + l15] = accA[r];
    } else if (w == 4) {
      f32x4 accS = (f32x4){0.f, 0.f, 0.f, 0.f};
      half8 kb0 = *(const half8*)((const char*)Ks_h[cur] + sw128(l15, g));
      half8 kb1 = *(const half8*)((const char*)Ks_h[cur] + sw128(l15, 4 + g));
      accS = MFMA16(a0, kb0, accS, 0, 0, 0);
      accS = MFMA16(a1, kb1, accS, 0, 0, 0);
#pragma unroll
      for (int r = 0; r < 4; ++r) {
        int t = g * 4 + r;
        Ss_h[t * 24 + l15] = (l15 < t) ? (_Float16)(-accS[r]) : (_Float16)0.f;
      }
    }
    __syncthreads();  // B2: tKs, Ss_h visible

    // ---- Phase B: LN fwd+bwd -> ue ----
#pragma unroll
    for (int i = 0; i < 2; ++i) {
      int t = i * 8 + w;
      float tkv = tKs[t][l];
      float s1 = wrs(tkv);
      float s2 = wrs(tkv * tkv);
      float mu = s1 * 0.015625f;
      float var = s2 * 0.015625f - mu * mu;
      float inv = rsqrtf(var + 1e-5f);
      float xhat = (tkv - mu) * inv;
      float ln = xhat * lw + lb;
      float gg = 0.125f * (Ksf[cur][t][l] + ln - Vsf[cur][t][l]);
      float dxh = gg * lw;
      float m1 = wrs(dxh) * 0.015625f;
      float m2 = wrs(dxh * xhat) * 0.015625f;
      float ue = (dxh - m1 - xhat * m2) * inv * Es[cur][t];
      UeT_h[l * 24 + t] = (_Float16)ue;
    }
    __syncthreads();  // B3: UeT_h visible

    // ---- Phase C: corr into qd-acc (waves 4-7), W-update (all), Wh refresh ----
    if (w >= 4) {
      half8 as = Z8, bu = Z8;
      if (g < 2) {
        as = *(const half8*)((const char*)Ss_h + l15 * 48 + g * 16);
        bu = *(const half8*)((const char*)UeT_h + ((w - 4) * 16 + l15) * 48 + g * 16);
      }
      accA = MFMA16(as, bu, accA, 0, 0, 0);  // adds (-S)@ue = -corr  => TQ
#pragma unroll
      for (int r = 0; r < 4; ++r) tqs[g * 4 + r][(w - 4) * 16 + l15] = accA[r];
    }
    {
      half8 au = Z8, bk0 = Z8, bk1 = Z8;
      if (g < 2) {
        au = *(const half8*)((const char*)UeT_h + (ti * 16 + l15) * 48 + g * 16);
        bk0 = *(const half8*)((const char*)KT_h[cur] + (tj0 * 16 + l15) * 48 + g * 16);
        bk1 = *(const half8*)((const char*)KT_h[cur] + (tj1 * 16 + l15) * 48 + g * 16);
      }
      accW0 = MFMA16(au, bk0, accW0, 0, 0, 0);  // adds ue^T@(-K) = -Ue^T@K
      accW1 = MFMA16(au, bk1, accW1, 0, 0, 0);
#pragma unroll
      for (int r = 0; r < 4; ++r) {
        int e = ti * 16 + g * 4 + r;
        *(_Float16*)((char*)Wh + sw128(e, d0 >> 3) + (d0 & 7) * 2) = (_Float16)accW0[r];
        *(_Float16*)((char*)Wh + sw128(e, d1 >> 3) + (d1 & 7) * 2) = (_Float16)accW1[r];
      }
    }
    __syncthreads();  // B4: tqs, (Wh for next step) visible

    // ---- Phase D: LN(TQ) -> z ; stage next chunk ----
#pragma unroll
    for (int i = 0; i < 2; ++i) {
      int t = i * 8 + w;
      float tq = tqs[t][l];
      float s1 = wrs(tq);
      float s2 = wrs(tq * tq);
      float mu = s1 * 0.015625f;
      float var = s2 * 0.015625f - mu * mu;
      float inv = rsqrtf(var + 1e-5f);
      float zv = Qsf[cur][t][l] + ((tq - mu) * inv) * lw + lb;
      zg[((size_t)(b * T_ + c * BT_ + t)) * DM_ + h * 64 + l] = (_Float16)zv;
    }
    if (pf) {
      if (tid < 256) {
        int r = tid >> 4, c4 = (tid & 15) * 4;
        *(float4*)&Ksf[nxt][r][c4] = fk;
        *(float4*)&Vsf[nxt][r][c4] = fv;
        half4 hk = {(_Float16)fk.x, (_Float16)fk.y, (_Float16)fk.z, (_Float16)fk.w};
        *(half4*)((char*)Ks_h[nxt] + sw128(r, c4 >> 3) + (c4 & 7) * 2) = hk;
        const float* fkp = &fk.x;
#pragma unroll
        for (int i = 0; i < 4; ++i)
          *(_Float16*)((char*)KT_h[nxt] + (c4 + i) * 48 + r * 2) = (_Float16)(-fkp[i]);
        if (tid < 16) Es[nxt][tid] = fe;
      } else {
        int t2 = tid - 256;
        int r = t2 >> 4, c4 = (t2 & 15) * 4;
        *(float4*)&Qsf[nxt][r][c4] = fq;
        half4 hq = {(_Float16)fq.x, (_Float16)fq.y, (_Float16)fq.z, (_Float16)fq.w};
        *(half4*)((char*)Qs_h[nxt] + sw128(r, c4 >> 3) + (c4 & 7) * 2) = hq;
      }
    }
  }

  // ---- final W dump ----
#pragma unroll
  for (int r = 0; r < 4; ++r) {
    int e = ti * 16 + g * 4 + r;
    wf[(size_t)bh * 4096 + e * 64 + d0] = accW0[r];
    wf[(size_t)bh * 4096 + e * 64 + d1] = accW1[r];
  }
}

extern "C" void kernel_launch(void* const* d_in, const int* in_sizes, int n_in,
                              void* d_out, int out_size, void* d_ws, size_t ws_size,
                              hipStream_t stream) {
  const float* x   = (const float*)d_in[0];
  const float* W0  = (const float*)d_in[1];
  const float* Wq  = (const float*)d_in[2];
  const float* Wk  = (const float*)d_in[3];
  const float* Wv  = (const float*)d_in[4];
  const float* Wo  = (const float*)d_in[5];
  const float* Wlr = (const float*)d_in[6];
  const float* lnw = (const float*)d_in[7];
  const float* lnb = (const float*)d_in[8];
  float* out = (float*)d_out;
  float* ws = (float*)d_ws;

  float* q    = ws;                      // 8,388,608 f
  float* k    = q + 8388608;             // 8,388,608 f
  float* v    = k + 8388608;             // 8,388,608 f
  float* eta  = v + 8388608;             // 8192 f
  float* cosT = eta + 8192;              // 65536 f
  float* sinT = cosT + 65536;            // 65536 f
  _Float16* xh = (_Float16*)(sinT + 65536);  // 8,388,608 halves
  _Float16* wh = xh + 8388608;               // 4x 1,048,576 halves
  _Float16* zh = xh;                         // alias: xh dead after qkv GEMM
  float* wf = out + 8388608;             // output #2: final W

  hipLaunchKernelGGL(k_rope_table, dim3(256), dim3(256), 0, stream, cosT, sinT);
  hipLaunchKernelGGL(k_cvt, dim3(6144), dim3(256), 0, stream, x, Wq, Wk, Wv, Wo, xh, wh);
  hipLaunchKernelGGL(k_eta, dim3(2048), dim3(256), 0, stream, x, Wlr, eta);
  hipLaunchKernelGGL(k_gemm_qkv_h, dim3(64, 24), dim3(256), 0, stream, xh, wh, cosT, sinT, q, k, v);
  hipLaunchKernelGGL(k_scan, dim3(64), dim3(512), 0, stream, q, k, v, eta, W0, lnw, lnb, zh, wf);
  hipLaunchKernelGGL(k_gemm_out_h, dim3(64, 8), dim3(256), 0, stream, zh, wh + 3145728, out);
}

// Round 5
// 426.529 us; speedup vs baseline: 4.7610x; 1.5444x over previous
//
#include <hip/hip_runtime.h>
#include <math.h>

#define B_ 4
#define T_ 2048
#define DM_ 1024
#define H_ 16
#define D_ 64
#define BT_ 16
#define NC_ 128

typedef _Float16 half8 __attribute__((ext_vector_type(8)));
typedef _Float16 half4 __attribute__((ext_vector_type(4)));
typedef float f32x4 __attribute__((ext_vector_type(4)));

#define MFMA16 __builtin_amdgcn_mfma_f32_16x16x32_f16

// ---- async global->LDS: 16B per lane, wave-uniform LDS base + lane*16 ----
__device__ __forceinline__ void stage16(const _Float16* g, _Float16* l) {
  __builtin_amdgcn_global_load_lds(
      (const __attribute__((address_space(1))) unsigned int*)(const void*)g,
      (__attribute__((address_space(3))) unsigned int*)(void*)l, 16, 0, 0);
}

// ---- fast wave64 all-reduce sum: DPP prefix + row_bcast + readlane ----
template <int CTRL>
__device__ __forceinline__ float dppadd(float x) {
  return x + __int_as_float(__builtin_amdgcn_update_dpp(0, __float_as_int(x), CTRL, 0xf, 0xf, true));
}
__device__ __forceinline__ float wrs(float v) {
  v = dppadd<0x111>(v);
  v = dppadd<0x112>(v);
  v = dppadd<0x114>(v);
  v = dppadd<0x118>(v);
  v = dppadd<0x142>(v);
  v = dppadd<0x143>(v);
  return __int_as_float(__builtin_amdgcn_readlane(__float_as_int(v), 63));
}

// byte offset into a [rows][64] f16 tile stored as 128B rows, 16B slots XOR-swizzled
__device__ __forceinline__ int sw128(int row, int slot) {
  return row * 128 + ((slot ^ (row & 7)) * 16);
}

// ---------------- RoPE tables: cos/sin (T x 32) ----------------
__global__ void k_rope_table(float* __restrict__ cosT, float* __restrict__ sinT) {
  int idx = blockIdx.x * blockDim.x + threadIdx.x;
  if (idx >= T_ * 32) return;
  int t = idx >> 5, i = idx & 31;
  float inv = powf(10000.0f, -((float)(2 * i)) / 64.0f);
  float f = (float)t * inv;
  cosT[idx] = cosf(f);
  sinT[idx] = sinf(f);
}

// ---------------- eta = 0.01*sigmoid(x @ Wlr^T) ----------------
__global__ __launch_bounds__(256) void k_eta(const float* __restrict__ x,
                                             const float* __restrict__ Wlr,
                                             float* __restrict__ eta) {
  int w = threadIdx.x >> 6, l = threadIdx.x & 63;
  int row = blockIdx.x * 4 + w;
  const float* xr = x + (size_t)row * DM_;
  float s = 0.f;
#pragma unroll
  for (int j = 0; j < DM_ / 64; ++j) s += xr[j * 64 + l] * Wlr[j * 64 + l];
  s = wrs(s);
  if (l == 0) eta[row] = 0.01f / (1.0f + expf(-s));
}

// ---------------- fp32 -> fp16 conversion: x and Wq/Wk/Wv/Wo ----------------
__global__ __launch_bounds__(256) void k_cvt(const float* __restrict__ x,
                                             const float* __restrict__ Wq,
                                             const float* __restrict__ Wk,
                                             const float* __restrict__ Wv,
                                             const float* __restrict__ Wo,
                                             _Float16* __restrict__ xh,
                                             _Float16* __restrict__ wh) {
  int gid = blockIdx.x * 256 + threadIdx.x;
  const float* src;
  _Float16* dst;
  size_t off;
  if (gid < 1048576) {
    src = x; dst = xh; off = (size_t)gid * 8;
  } else {
    int j = gid - 1048576;
    int sel = j >> 17, jj = j & 131071;
    src = (sel == 0) ? Wq : (sel == 1) ? Wk : (sel == 2) ? Wv : Wo;
    dst = wh + (size_t)sel * 1048576;
    off = (size_t)jj * 8;
  }
  float4 a = *(const float4*)&src[off];
  float4 b = *(const float4*)&src[off + 4];
  half8 h;
  h[0] = (_Float16)a.x; h[1] = (_Float16)a.y; h[2] = (_Float16)a.z; h[3] = (_Float16)a.w;
  h[4] = (_Float16)b.x; h[5] = (_Float16)b.y; h[6] = (_Float16)b.z; h[7] = (_Float16)b.w;
  *(half8*)&dst[off] = h;
}

// ---------------- QKV GEMM (f16 MFMA, gload_lds staging) + fused RoPE, fp16 out ----------------
// grid (64, 24): by>>3 = mat (q/k/v), by&7 = n-tile
__global__ __launch_bounds__(256) void k_gemm_qkv_h(const _Float16* __restrict__ xh,
                                                    const _Float16* __restrict__ wh,
                                                    const float* __restrict__ cosT,
                                                    const float* __restrict__ sinT,
                                                    _Float16* __restrict__ qo,
                                                    _Float16* __restrict__ ko,
                                                    _Float16* __restrict__ vo) {
  __shared__ __align__(16) union {
    _Float16 ab[2][128 * 64];
    _Float16 ep[128][136];
  } sm;
  _Float16* As = sm.ab[0];
  _Float16* Bs = sm.ab[1];
  int tid = threadIdx.x;
  int m0 = blockIdx.x * 128;
  int by = blockIdx.y;
  int mat = by >> 3;
  int n0 = (by & 7) * 128;
  const _Float16* Bsrc = wh + (size_t)mat * 1048576;
  _Float16* op = (mat == 0) ? qo : (mat == 1) ? ko : vo;
  int wid = tid >> 6, l = tid & 63;
  int m0w = (wid >> 1) * 64, n0w = (wid & 1) * 64;
  int l15 = l & 15, l4 = l >> 4;

  f32x4 acc[4][4];
#pragma unroll
  for (int i = 0; i < 4; ++i)
#pragma unroll
    for (int j = 0; j < 4; ++j) acc[i][j] = (f32x4){0.f, 0.f, 0.f, 0.f};

  // staging geometry: wave w stages rows [w*32, w*32+32) of A and B, 4 calls each
  int srow_in = l >> 3;            // 0..7 within call
  int schunk_l = l & 7;            // LDS chunk = lane%8 (linear dest)
  for (int k0 = 0; k0 < 1024; k0 += 64) {
#pragma unroll
    for (int i = 0; i < 4; ++i) {
      int row = wid * 32 + i * 8 + srow_in;
      int sc = schunk_l ^ (row & 7);  // pre-swizzled source chunk
      stage16(xh + (size_t)(m0 + row) * 1024 + k0 + sc * 8, As + (wid * 32 + i * 8) * 64);
      stage16(Bsrc + (size_t)(n0 + row) * 1024 + k0 + sc * 8, Bs + (wid * 32 + i * 8) * 64);
    }
    __syncthreads();  // vmcnt(0) drain + barrier
#pragma unroll
    for (int kk = 0; kk < 2; ++kk) {
      half8 a[4], b[4];
#pragma unroll
      for (int mi = 0; mi < 4; ++mi) {
        int row = m0w + mi * 16 + l15;
        a[mi] = *(half8*)((char*)As + sw128(row, kk * 4 + l4));
      }
#pragma unroll
      for (int ni = 0; ni < 4; ++ni) {
        int row = n0w + ni * 16 + l15;
        b[ni] = *(half8*)((char*)Bs + sw128(row, kk * 4 + l4));
      }
#pragma unroll
      for (int mi = 0; mi < 4; ++mi)
#pragma unroll
        for (int ni = 0; ni < 4; ++ni)
          acc[mi][ni] = MFMA16(a[mi], b[ni], acc[mi][ni], 0, 0, 0);
    }
    __syncthreads();
  }

  // fused RoPE (q,k): pair (d, d+32) = (ni, ni+2), register-local
  if (mat < 2) {
#pragma unroll
    for (int mi = 0; mi < 4; ++mi)
#pragma unroll
      for (int r = 0; r < 4; ++r) {
        int m = m0 + m0w + mi * 16 + l4 * 4 + r;
        int t = m & (T_ - 1);
#pragma unroll
        for (int ni = 0; ni < 2; ++ni) {
          int d1 = ni * 16 + l15;
          float cv = cosT[t * 32 + d1];
          float sv = sinT[t * 32 + d1];
          float x1 = acc[mi][ni][r], x2 = acc[mi][ni + 2][r];
          acc[mi][ni][r] = x1 * cv - x2 * sv;
          acc[mi][ni + 2][r] = x2 * cv + x1 * sv;
        }
      }
  }

  // epilogue: stage fp16 tile in LDS, then fully-coalesced half8 stores
#pragma unroll
  for (int mi = 0; mi < 4; ++mi)
#pragma unroll
    for (int ni = 0; ni < 4; ++ni)
#pragma unroll
      for (int r = 0; r < 4; ++r) {
        int mrow = m0w + mi * 16 + l4 * 4 + r;
        int ncol = n0w + ni * 16 + l15;
        sm.ep[mrow][ncol] = (_Float16)acc[mi][ni][r];
      }
  __syncthreads();
  int bb = m0 >> 11, t0 = m0 & (T_ - 1);
#pragma unroll
  for (int seg = 0; seg < 2; ++seg) {
    int h0 = (by & 7) * 2 + seg;
    _Float16* dsth = op + ((size_t)(bb * H_ + h0) * T_ + t0) * D_;
#pragma unroll
    for (int p = 0; p < 4; ++p) {
      int idx = p * 256 + tid;
      int mrow = idx >> 3, c = idx & 7;
      half8 hv = *(half8*)&sm.ep[mrow][seg * 64 + c * 8];
      *(half8*)&dsth[mrow * 64 + c * 8] = hv;
    }
  }
}

// ---------------- out = zh @ Wo^T (fp32 out, coalesced epilogue) ----------------
__global__ __launch_bounds__(256) void k_gemm_out_h(const _Float16* __restrict__ zh,
                                                    const _Float16* __restrict__ woh,
                                                    float* __restrict__ out) {
  __shared__ __align__(16) union {
    _Float16 ab[2][128 * 64];
    float epf[64][132];
  } sm;
  _Float16* As = sm.ab[0];
  _Float16* Bs = sm.ab[1];
  int tid = threadIdx.x;
  int m0 = blockIdx.x * 128;
  int n0 = blockIdx.y * 128;
  int wid = tid >> 6, l = tid & 63;
  int m0w = (wid >> 1) * 64, n0w = (wid & 1) * 64;
  int l15 = l & 15, l4 = l >> 4;

  f32x4 acc[4][4];
#pragma unroll
  for (int i = 0; i < 4; ++i)
#pragma unroll
    for (int j = 0; j < 4; ++j) acc[i][j] = (f32x4){0.f, 0.f, 0.f, 0.f};

  int srow_in = l >> 3;
  int schunk_l = l & 7;
  for (int k0 = 0; k0 < 1024; k0 += 64) {
#pragma unroll
    for (int i = 0; i < 4; ++i) {
      int row = wid * 32 + i * 8 + srow_in;
      int sc = schunk_l ^ (row & 7);
      stage16(zh + (size_t)(m0 + row) * 1024 + k0 + sc * 8, As + (wid * 32 + i * 8) * 64);
      stage16(woh + (size_t)(n0 + row) * 1024 + k0 + sc * 8, Bs + (wid * 32 + i * 8) * 64);
    }
    __syncthreads();
#pragma unroll
    for (int kk = 0; kk < 2; ++kk) {
      half8 a[4], b[4];
#pragma unroll
      for (int mi = 0; mi < 4; ++mi) {
        int row = m0w + mi * 16 + l15;
        a[mi] = *(half8*)((char*)As + sw128(row, kk * 4 + l4));
      }
#pragma unroll
      for (int ni = 0; ni < 4; ++ni) {
        int row = n0w + ni * 16 + l15;
        b[ni] = *(half8*)((char*)Bs + sw128(row, kk * 4 + l4));
      }
#pragma unroll
      for (int mi = 0; mi < 4; ++mi)
#pragma unroll
        for (int ni = 0; ni < 4; ++ni)
          acc[mi][ni] = MFMA16(a[mi], b[ni], acc[mi][ni], 0, 0, 0);
    }
    __syncthreads();
  }

  // epilogue: two fp32 half-tiles via LDS, coalesced float4 stores
#pragma unroll
  for (int hi = 0; hi < 2; ++hi) {
    if ((wid >> 1) == hi) {
#pragma unroll
      for (int mi = 0; mi < 4; ++mi)
#pragma unroll
        for (int ni = 0; ni < 4; ++ni)
#pragma unroll
          for (int r = 0; r < 4; ++r)
            sm.epf[mi * 16 + l4 * 4 + r][n0w + ni * 16 + l15] = acc[mi][ni][r];
    }
    __syncthreads();
#pragma unroll
    for (int p = 0; p < 8; ++p) {
      int idx = p * 256 + tid;
      int mrow = idx >> 5, c = idx & 31;
      float4 v = *(float4*)&sm.epf[mrow][c * 4];
      *(float4*)&out[(size_t)(m0 + hi * 64 + mrow) * DM_ + n0 + c * 4] = v;
    }
    __syncthreads();
  }
}

// ---------------- TTT scan: MFMA-based, 1 block/(b,h), 8 waves (fp16 q/k/v inputs) ----------------
__global__ __launch_bounds__(512) void k_scan(const _Float16* __restrict__ qg,
                                              const _Float16* __restrict__ kg,
                                              const _Float16* __restrict__ vg,
                                              const float* __restrict__ etag,
                                              const float* __restrict__ W0,
                                              const float* __restrict__ lnw_g,
                                              const float* __restrict__ lnb_g,
                                              _Float16* __restrict__ zg,
                                              float* __restrict__ wf) {
  __shared__ __align__(16) float Ksf[2][16][68], Qsf[2][16][68], Vsf[2][16][68];
  __shared__ __align__(16) _Float16 Ks_h[2][1024], Qs_h[2][1024];  // 16 x 128B swizzled rows
  __shared__ __align__(16) _Float16 KT_h[2][64 * 24];              // [d][t], stride 24, = -K
  __shared__ __align__(16) _Float16 Wh[64 * 64];                   // [e][d] swizzled, fp16 W
  __shared__ __align__(16) float tKs[16][68], tqs[16][68];
  __shared__ __align__(16) _Float16 Ss_h[16 * 24];                 // [t][s], = -S masked
  __shared__ __align__(16) _Float16 UeT_h[64 * 24];                // [e][t], = +ue
  __shared__ float Es[2][16];

  int bh = blockIdx.x, b = bh >> 4, h = bh & 15;
  int tid = threadIdx.x, w = tid >> 6, l = tid & 63;
  int l15 = l & 15, g = l >> 4;
  int ti = w >> 1, tj0 = (w & 1) * 2, tj1 = tj0 + 1;
  int d0 = tj0 * 16 + l15, d1 = tj1 * 16 + l15;

  float lw = lnw_g[h * 64 + l];
  float lb = lnb_g[h * 64 + l];
  const _Float16* kb = kg + (size_t)bh * (T_ * D_);
  const _Float16* qb = qg + (size_t)bh * (T_ * D_);
  const _Float16* vb = vg + (size_t)bh * (T_ * D_);

  // ---- W0 -> accumulators + initial Wh ----
  const float* w0p = W0 + (size_t)bh * 4096;
  f32x4 accW0, accW1;
#pragma unroll
  for (int r = 0; r < 4; ++r) {
    int e = ti * 16 + g * 4 + r;
    accW0[r] = w0p[e * 64 + d0];
    accW1[r] = w0p[e * 64 + d1];
  }
#pragma unroll
  for (int r = 0; r < 4; ++r) {
    int e = ti * 16 + g * 4 + r;
    *(_Float16*)((char*)Wh + sw128(e, d0 >> 3) + (d0 & 7) * 2) = (_Float16)accW0[r];
    *(_Float16*)((char*)Wh + sw128(e, d1 >> 3) + (d1 & 7) * 2) = (_Float16)accW1[r];
  }

  // ---- stage chunk 0 ----
  {
    if (tid < 256) {
      int r = tid >> 4, c4 = (tid & 15) * 4;
      half4 fk = *(const half4*)&kb[r * 64 + c4];
      half4 fv = *(const half4*)&vb[r * 64 + c4];
#pragma unroll
      for (int i = 0; i < 4; ++i) {
        Ksf[0][r][c4 + i] = (float)fk[i];
        Vsf[0][r][c4 + i] = (float)fv[i];
        *(_Float16*)((char*)KT_h[0] + (c4 + i) * 48 + r * 2) = (_Float16)(-(float)fk[i]);
      }
      *(half4*)((char*)Ks_h[0] + sw128(r, c4 >> 3) + (c4 & 7) * 2) = fk;
      if (tid < 16) Es[0][tid] = etag[b * T_ + tid];
    } else {
      int t2 = tid - 256;
      int r = t2 >> 4, c4 = (t2 & 15) * 4;
      half4 fq = *(const half4*)&qb[r * 64 + c4];
#pragma unroll
      for (int i = 0; i < 4; ++i) Qsf[0][r][c4 + i] = (float)fq[i];
      *(half4*)((char*)Qs_h[0] + sw128(r, c4 >> 3) + (c4 & 7) * 2) = fq;
    }
  }

  const half8 Z8 = {0, 0, 0, 0, 0, 0, 0, 0};

  for (int c = 0; c < NC_; ++c) {
    int cur = c & 1, nxt = cur ^ 1;
    __syncthreads();  // B1: buf[cur] + Wh visible

    bool pf = (c + 1 < NC_);
    half4 fk, fv, fq;
    float fe = 0.f;
    if (pf) {
      int goff = (c + 1) * (BT_ * D_);
      if (tid < 256) {
        int r = tid >> 4, c4 = (tid & 15) * 4;
        fk = *(const half4*)&kb[goff + r * 64 + c4];
        fv = *(const half4*)&vb[goff + r * 64 + c4];
        if (tid < 16) fe = etag[b * T_ + (c + 1) * BT_ + tid];
      } else {
        int t2 = tid - 256;
        int r = t2 >> 4, c4 = (t2 & 15) * 4;
        fq = *(const half4*)&qb[goff + r * 64 + c4];
      }
    }

    // ---- Phase A: MFMA tK / qd / S ----
    int j = w & 3;
    const _Float16* Asrc = (w < 4) ? Ks_h[cur] : Qs_h[cur];
    half8 a0 = *(const half8*)((const char*)Asrc + sw128(l15, g));
    half8 a1 = *(const half8*)((const char*)Asrc + sw128(l15, 4 + g));
    int ecol = j * 16 + l15;
    half8 b0 = *(const half8*)((const char*)Wh + sw128(ecol, g));
    half8 b1 = *(const half8*)((const char*)Wh + sw128(ecol, 4 + g));
    f32x4 accA = (f32x4){0.f, 0.f, 0.f, 0.f};
    accA = MFMA16(a0, b0, accA, 0, 0, 0);
    accA = MFMA16(a1, b1, accA, 0, 0, 0);
    if (w < 4) {
#pragma unroll
      for (int r = 0; r < 4; ++r) tKs[g * 4 + r][j * 16 + l15] = accA[r];
    } else if (w == 4) {
      f32x4 accS = (f32x4){0.f, 0.f, 0.f, 0.f};
      half8 kb0 = *(const half8*)((const char*)Ks_h[cur] + sw128(l15, g));
      half8 kb1 = *(const half8*)((const char*)Ks_h[cur] + sw128(l15, 4 + g));
      accS = MFMA16(a0, kb0, accS, 0, 0, 0);
      accS = MFMA16(a1, kb1, accS, 0, 0, 0);
#pragma unroll
      for (int r = 0; r < 4; ++r) {
        int t = g * 4 + r;
        Ss_h[t * 24 + l15] = (l15 < t) ? (_Float16)(-accS[r]) : (_Float16)0.f;
      }
    }
    __syncthreads();  // B2: tKs, Ss_h visible

    // ---- Phase B: LN fwd+bwd -> ue ----
#pragma unroll
    for (int i = 0; i < 2; ++i) {
      int t = i * 8 + w;
      float tkv = tKs[t][l];
      float s1 = wrs(tkv);
      float s2 = wrs(tkv * tkv);
      float mu = s1 * 0.015625f;
      float var = s2 * 0.015625f - mu * mu;
      float inv = rsqrtf(var + 1e-5f);
      float xhat = (tkv - mu) * inv;
      float ln = xhat * lw + lb;
      float gg = 0.125f * (Ksf[cur][t][l] + ln - Vsf[cur][t][l]);
      float dxh = gg * lw;
      float m1 = wrs(dxh) * 0.015625f;
      float m2 = wrs(dxh * xhat) * 0.015625f;
      float ue = (dxh - m1 - xhat * m2) * inv * Es[cur][t];
      UeT_h[l * 24 + t] = (_Float16)ue;
    }
    __syncthreads();  // B3: UeT_h visible

    // ---- Phase C: corr into qd-acc (waves 4-7), W-update (all), Wh refresh ----
    if (w >= 4) {
      half8 as = Z8, bu = Z8;
      if (g < 2) {
        as = *(const half8*)((const char*)Ss_h + l15 * 48 + g * 16);
        bu = *(const half8*)((const char*)UeT_h + ((w - 4) * 16 + l15) * 48 + g * 16);
      }
      accA = MFMA16(as, bu, accA, 0, 0, 0);  // adds (-S)@ue = -corr  => TQ
#pragma unroll
      for (int r = 0; r < 4; ++r) tqs[g * 4 + r][(w - 4) * 16 + l15] = accA[r];
    }
    {
      half8 au = Z8, bk0 = Z8, bk1 = Z8;
      if (g < 2) {
        au = *(const half8*)((const char*)UeT_h + (ti * 16 + l15) * 48 + g * 16);
        bk0 = *(const half8*)((const char*)KT_h[cur] + (tj0 * 16 + l15) * 48 + g * 16);
        bk1 = *(const half8*)((const char*)KT_h[cur] + (tj1 * 16 + l15) * 48 + g * 16);
      }
      accW0 = MFMA16(au, bk0, accW0, 0, 0, 0);  // adds ue^T@(-K) = -Ue^T@K
      accW1 = MFMA16(au, bk1, accW1, 0, 0, 0);
#pragma unroll
      for (int r = 0; r < 4; ++r) {
        int e = ti * 16 + g * 4 + r;
        *(_Float16*)((char*)Wh + sw128(e, d0 >> 3) + (d0 & 7) * 2) = (_Float16)accW0[r];
        *(_Float16*)((char*)Wh + sw128(e, d1 >> 3) + (d1 & 7) * 2) = (_Float16)accW1[r];
      }
    }
    __syncthreads();  // B4: tqs, (Wh for next step) visible

    // ---- Phase D: LN(TQ) -> z ; stage next chunk ----
#pragma unroll
    for (int i = 0; i < 2; ++i) {
      int t = i * 8 + w;
      float tq = tqs[t][l];
      float s1 = wrs(tq);
      float s2 = wrs(tq * tq);
      float mu = s1 * 0.015625f;
      float var = s2 * 0.015625f - mu * mu;
      float inv = rsqrtf(var + 1e-5f);
      float zv = Qsf[cur][t][l] + ((tq - mu) * inv) * lw + lb;
      zg[((size_t)(b * T_ + c * BT_ + t)) * DM_ + h * 64 + l] = (_Float16)zv;
    }
    if (pf) {
      if (tid < 256) {
        int r = tid >> 4, c4 = (tid & 15) * 4;
#pragma unroll
        for (int i = 0; i < 4; ++i) {
          Ksf[nxt][r][c4 + i] = (float)fk[i];
          Vsf[nxt][r][c4 + i] = (float)fv[i];
          *(_Float16*)((char*)KT_h[nxt] + (c4 + i) * 48 + r * 2) = (_Float16)(-(float)fk[i]);
        }
        *(half4*)((char*)Ks_h[nxt] + sw128(r, c4 >> 3) + (c4 & 7) * 2) = fk;
        if (tid < 16) Es[nxt][tid] = fe;
      } else {
        int t2 = tid - 256;
        int r = t2 >> 4, c4 = (t2 & 15) * 4;
#pragma unroll
        for (int i = 0; i < 4; ++i) Qsf[nxt][r][c4 + i] = (float)fq[i];
        *(half4*)((char*)Qs_h[nxt] + sw128(r, c4 >> 3) + (c4 & 7) * 2) = fq;
      }
    }
  }

  // ---- final W dump ----
#pragma unroll
  for (int r = 0; r < 4; ++r) {
    int e = ti * 16 + g * 4 + r;
    wf[(size_t)bh * 4096 + e * 64 + d0] = accW0[r];
    wf[(size_t)bh * 4096 + e * 64 + d1] = accW1[r];
  }
}

extern "C" void kernel_launch(void* const* d_in, const int* in_sizes, int n_in,
                              void* d_out, int out_size, void* d_ws, size_t ws_size,
                              hipStream_t stream) {
  const float* x   = (const float*)d_in[0];
  const float* W0  = (const float*)d_in[1];
  const float* Wq  = (const float*)d_in[2];
  const float* Wk  = (const float*)d_in[3];
  const float* Wv  = (const float*)d_in[4];
  const float* Wo  = (const float*)d_in[5];
  const float* Wlr = (const float*)d_in[6];
  const float* lnw = (const float*)d_in[7];
  const float* lnb = (const float*)d_in[8];
  float* out = (float*)d_out;
  float* ws = (float*)d_ws;

  float* eta  = ws;                          // 8192 f
  float* cosT = eta + 8192;                  // 65536 f
  float* sinT = cosT + 65536;                // 65536 f
  _Float16* q  = (_Float16*)(sinT + 65536);  // 8,388,608 halves (B,H,T,D)
  _Float16* k  = q + 8388608;
  _Float16* v  = k + 8388608;
  _Float16* xh = v + 8388608;                // 8,388,608 halves
  _Float16* wh = xh + 8388608;               // 4x 1,048,576 halves
  _Float16* zh = xh;                         // alias: xh dead after qkv GEMM
  float* wf = out + 8388608;                 // output #2: final W

  hipLaunchKernelGGL(k_rope_table, dim3(256), dim3(256), 0, stream, cosT, sinT);
  hipLaunchKernelGGL(k_cvt, dim3(6144), dim3(256), 0, stream, x, Wq, Wk, Wv, Wo, xh, wh);
  hipLaunchKernelGGL(k_eta, dim3(2048), dim3(256), 0, stream, x, Wlr, eta);
  hipLaunchKernelGGL(k_gemm_qkv_h, dim3(64, 24), dim3(256), 0, stream, xh, wh, cosT, sinT, q, k, v);
  hipLaunchKernelGGL(k_scan, dim3(64), dim3(512), 0, stream, q, k, v, eta, W0, lnw, lnb, zh, wf);
  hipLaunchKernelGGL(k_gemm_out_h, dim3(64, 8), dim3(256), 0, stream, zh, wh + 3145728, out);
}